// Round 1
// baseline (205.824 us; speedup 1.0000x reference)
//
#include <hip/hip_runtime.h>
#include <hip/hip_bf16.h>

#define BATCH 16
#define C 768
#define T 8
#define R 64
#define HW 4096
#define NPS (HW*C)   // 3145728 elements per sample
#define GN_EPS 1e-5f

typedef short bf16x8 __attribute__((ext_vector_type(8)));
typedef float f32x4 __attribute__((ext_vector_type(4)));

static __device__ __forceinline__ unsigned short f2bf(float f) {
    __hip_bfloat16 h = __float2bfloat16(f);
    return *reinterpret_cast<unsigned short*>(&h);
}

// ---------------- kernel 1: zero stats + convert weights to bf16 ----------------
__global__ __launch_bounds__(256) void prep_kernel(const float* __restrict__ Wdn,
                                                   const float* __restrict__ Wup,
                                                   float* __restrict__ stats,
                                                   unsigned short* __restrict__ wd_bf,
                                                   unsigned short* __restrict__ wu_bf) {
    int idx = blockIdx.x * 256 + threadIdx.x;   // 0..196607, each handles one float4
    if (blockIdx.x == 0 && threadIdx.x < 32) stats[threadIdx.x] = 0.f;
    const int NF4 = T * R * C / 4;              // 98304 float4 per weight tensor
    const float4* src;
    unsigned short* dst;
    int j;
    if (idx < NF4) { src = (const float4*)Wdn; dst = wd_bf; j = idx; }
    else           { src = (const float4*)Wup; dst = wu_bf; j = idx - NF4; }
    float4 v = src[j];
    ushort4 o;
    o.x = f2bf(v.x); o.y = f2bf(v.y); o.z = f2bf(v.z); o.w = f2bf(v.w);
    *reinterpret_cast<ushort4*>(dst + j * 4) = o;
}

// ---------------- kernel 2: per-sample sum / sumsq ----------------
__global__ __launch_bounds__(256) void stats_kernel(const float* __restrict__ x,
                                                    float* __restrict__ stats) {
    int b = blockIdx.y;
    const float4* xp = (const float4*)(x + (size_t)b * NPS);
    float s = 0.f, q = 0.f;
    int base = blockIdx.x * 256 + threadIdx.x;  // grid.x = 48 -> 12288 threads
    #pragma unroll 4
    for (int i = 0; i < 64; i++) {
        float4 v = xp[(size_t)i * 12288 + base];
        s += v.x + v.y + v.z + v.w;
        q += v.x*v.x + v.y*v.y + v.z*v.z + v.w*v.w;
    }
    for (int off = 32; off > 0; off >>= 1) {
        s += __shfl_down(s, off);
        q += __shfl_down(q, off);
    }
    __shared__ float ps[4], pq[4];
    int wave = threadIdx.x >> 6, lane = threadIdx.x & 63;
    if (lane == 0) { ps[wave] = s; pq[wave] = q; }
    __syncthreads();
    if (threadIdx.x == 0) {
        float S = 0.f, Q = 0.f;
        #pragma unroll
        for (int wv = 0; wv < 4; wv++) { S += ps[wv]; Q += pq[wv]; }
        atomicAdd(&stats[2*b],   S);
        atomicAdd(&stats[2*b+1], Q);
    }
}

// ---------------- kernel 3: fused normalize + GEMM1 + gelu + GEMM2 + residual ----------------
// grid (64 tiles, 16 samples), 256 threads = 4 waves, 64 rows per tile
__global__ __launch_bounds__(256) void fused_kernel(
        const float* __restrict__ x, const int* __restrict__ task_ids,
        const float* __restrict__ gamma, const float* __restrict__ beta,
        const float* __restrict__ scales, const float* __restrict__ stats,
        const unsigned short* __restrict__ wd_bf, const unsigned short* __restrict__ wu_bf,
        float* __restrict__ out) {
    __shared__ unsigned short xs[64 * 768];   // 98304 B, XOR-swizzled bf16 x_norm
    __shared__ unsigned short hs[64 * 72];    // 9216 B, gelu(h), padded stride 72
    char* sb = (char*)xs;

    int tile = blockIdx.x, b = blockIdx.y;
    int tid = threadIdx.x;
    int t = task_ids[b];
    float sc = scales[t];
    float s1 = stats[2*b], s2 = stats[2*b+1];
    float mean = s1 * (1.f / NPS);
    float var  = s2 * (1.f / NPS) - mean * mean;
    float rstd = rsqrtf(var + GN_EPS);

    size_t xbase = (size_t)b * NPS + (size_t)tile * 64 * C;
    const float4* xp = (const float4*)(x + xbase);

    // ---- stage 64x768 normalized tile into LDS as bf16 (swizzled) ----
    for (int it = 0; it < 48; it++) {
        int f = it * 256 + tid;          // 0..12287 float4 index
        int row = f / 192;               // 192 float4 per row
        int c4  = f - row * 192;
        float4 v  = xp[f];
        float4 g  = ((const float4*)gamma)[c4];
        float4 bt = ((const float4*)beta)[c4];
        ushort4 o;
        o.x = f2bf((v.x - mean) * rstd * g.x + bt.x);
        o.y = f2bf((v.y - mean) * rstd * g.y + bt.y);
        o.z = f2bf((v.z - mean) * rstd * g.z + bt.z);
        o.w = f2bf((v.w - mean) * rstd * g.w + bt.w);
        int byte = row * 1536 + c4 * 8;
        byte ^= ((row & 7) << 4);
        *reinterpret_cast<ushort4*>(sb + byte) = o;
    }
    __syncthreads();

    int wave = tid >> 6, lane = tid & 63;
    int m0 = wave * 16;
    int lr = lane & 15, lg = lane >> 4;

    // ---- GEMM1: h[64 x 64] = x_norm[64 x 768] * Wd^T ----
    f32x4 acc1[4] = {};
    const unsigned short* wd = wd_bf + t * (R * C);
    for (int k = 0; k < 24; k++) {
        int arow = m0 + lr;
        int abyte = (arow * 1536 + k * 64 + lg * 16) ^ ((arow & 7) << 4);
        bf16x8 a = *reinterpret_cast<const bf16x8*>(sb + abyte);
        #pragma unroll
        for (int n = 0; n < 4; n++) {
            int r = n * 16 + lr;
            bf16x8 bb = *reinterpret_cast<const bf16x8*>(wd + r * C + k * 32 + lg * 8);
            acc1[n] = __builtin_amdgcn_mfma_f32_16x16x32_bf16(a, bb, acc1[n], 0, 0, 0);
        }
    }

    // ---- exact gelu, h -> LDS (bf16) ----
    #pragma unroll
    for (int n = 0; n < 4; n++) {
        #pragma unroll
        for (int j = 0; j < 4; j++) {
            float v = acc1[n][j];
            float gel = 0.5f * v * (1.f + erff(v * 0.70710678118f));
            int row = m0 + lg * 4 + j;
            int col = n * 16 + lr;
            hs[row * 72 + col] = f2bf(gel);
        }
    }
    __syncthreads();

    // ---- GEMM2: delta[64 x 768] = h[64 x 64] * Wu^T, fused residual ----
    bf16x8 a2[2];
    #pragma unroll
    for (int k2 = 0; k2 < 2; k2++) {
        int row = m0 + lr;
        a2[k2] = *reinterpret_cast<const bf16x8*>(hs + row * 72 + k2 * 32 + lg * 8);
    }
    const unsigned short* wu = wu_bf + t * (C * R);
    float* outp = out + xbase;
    const float* xr = x + xbase;
    for (int cn = 0; cn < 6; cn++) {
        f32x4 acc2[8] = {};
        #pragma unroll
        for (int nf = 0; nf < 8; nf++) {
            int cidx = cn * 128 + nf * 16 + lr;
            #pragma unroll
            for (int k2 = 0; k2 < 2; k2++) {
                bf16x8 bb = *reinterpret_cast<const bf16x8*>(wu + cidx * R + k2 * 32 + lg * 8);
                acc2[nf] = __builtin_amdgcn_mfma_f32_16x16x32_bf16(a2[k2], bb, acc2[nf], 0, 0, 0);
            }
        }
        #pragma unroll
        for (int nf = 0; nf < 8; nf++) {
            #pragma unroll
            for (int j = 0; j < 4; j++) {
                int row = m0 + lg * 4 + j;
                int col = cn * 128 + nf * 16 + lr;
                int idx = row * C + col;
                outp[idx] = xr[idx] + sc * acc2[nf][j];
            }
        }
    }
}

extern "C" void kernel_launch(void* const* d_in, const int* in_sizes, int n_in,
                              void* d_out, int out_size, void* d_ws, size_t ws_size,
                              hipStream_t stream) {
    const float* x        = (const float*)d_in[0];
    const int*   task_ids = (const int*)d_in[1];
    const float* gamma    = (const float*)d_in[2];
    const float* beta     = (const float*)d_in[3];
    const float* W_down   = (const float*)d_in[4];
    const float* W_up     = (const float*)d_in[5];
    const float* scales   = (const float*)d_in[6];
    float* out = (float*)d_out;

    // workspace layout: [0,128): stats (16 x {sum,sumsq}); then bf16 weights
    float* stats = (float*)d_ws;
    unsigned short* wd_bf = (unsigned short*)((char*)d_ws + 128);
    unsigned short* wu_bf = wd_bf + T * R * C;

    // 1) zero stats + convert weights (2*98304 float4 jobs / 256 = 768 blocks)
    prep_kernel<<<768, 256, 0, stream>>>(W_down, W_up, stats, wd_bf, wu_bf);
    // 2) per-sample stats
    stats_kernel<<<dim3(48, BATCH), 256, 0, stream>>>(x, stats);
    // 3) fused adapter
    fused_kernel<<<dim3(64, BATCH), 256, 0, stream>>>(
        x, task_ids, gamma, beta, scales, stats, wd_bf, wu_bf, out);
}

// Round 2
// 199.873 us; speedup vs baseline: 1.0298x; 1.0298x over previous
//
#include <hip/hip_runtime.h>
#include <hip/hip_bf16.h>

#define BATCH 16
#define C 768
#define T 8
#define R 64
#define HW 4096
#define NPS (HW*C)   // 3145728 elements per sample
#define GN_EPS 1e-5f

typedef short bf16x8 __attribute__((ext_vector_type(8)));
typedef float f32x4 __attribute__((ext_vector_type(4)));

static __device__ __forceinline__ unsigned short f2bf(float f) {
    __hip_bfloat16 h = __float2bfloat16(f);
    return *reinterpret_cast<unsigned short*>(&h);
}

// ---------------- kernel 1: zero stats + convert weights to bf16 ----------------
__global__ __launch_bounds__(256) void prep_kernel(const float* __restrict__ Wdn,
                                                   const float* __restrict__ Wup,
                                                   float* __restrict__ stats,
                                                   unsigned short* __restrict__ wd_bf,
                                                   unsigned short* __restrict__ wu_bf) {
    int idx = blockIdx.x * 256 + threadIdx.x;   // 0..196607, each handles one float4
    if (blockIdx.x == 0 && threadIdx.x < 32) stats[threadIdx.x] = 0.f;
    const int NF4 = T * R * C / 4;              // 98304 float4 per weight tensor
    const float4* src;
    unsigned short* dst;
    int j;
    if (idx < NF4) { src = (const float4*)Wdn; dst = wd_bf; j = idx; }
    else           { src = (const float4*)Wup; dst = wu_bf; j = idx - NF4; }
    float4 v = src[j];
    ushort4 o;
    o.x = f2bf(v.x); o.y = f2bf(v.y); o.z = f2bf(v.z); o.w = f2bf(v.w);
    *reinterpret_cast<ushort4*>(dst + j * 4) = o;
}

// ---------------- kernel 2: per-sample sum / sumsq ----------------
__global__ __launch_bounds__(256) void stats_kernel(const float* __restrict__ x,
                                                    float* __restrict__ stats) {
    int b = blockIdx.y;
    const float4* xp = (const float4*)(x + (size_t)b * NPS);
    float s = 0.f, q = 0.f;
    int base = blockIdx.x * 256 + threadIdx.x;  // grid.x = 48 -> 12288 threads
    #pragma unroll 4
    for (int i = 0; i < 64; i++) {
        float4 v = xp[(size_t)i * 12288 + base];
        s += v.x + v.y + v.z + v.w;
        q += v.x*v.x + v.y*v.y + v.z*v.z + v.w*v.w;
    }
    for (int off = 32; off > 0; off >>= 1) {
        s += __shfl_down(s, off);
        q += __shfl_down(q, off);
    }
    __shared__ float ps[4], pq[4];
    int wave = threadIdx.x >> 6, lane = threadIdx.x & 63;
    if (lane == 0) { ps[wave] = s; pq[wave] = q; }
    __syncthreads();
    if (threadIdx.x == 0) {
        float S = 0.f, Q = 0.f;
        #pragma unroll
        for (int wv = 0; wv < 4; wv++) { S += ps[wv]; Q += pq[wv]; }
        atomicAdd(&stats[2*b],   S);
        atomicAdd(&stats[2*b+1], Q);
    }
}

// ---------------- kernel 3: fused normalize + GEMM1 + gelu + GEMM2 + residual ----------------
// grid (64 tiles, 16 samples), 256 threads = 4 waves, each wave owns a 16-row strip.
// No x staging in LDS: MFMA A-fragments are loaded straight from global (L3-resident
// after the stats pass), normalized in-register. LDS holds only gelu(h) (9 KiB)
// -> 4 blocks/CU via __launch_bounds__(256,4).
__global__ __launch_bounds__(256, 4) void fused_kernel(
        const float* __restrict__ x, const int* __restrict__ task_ids,
        const float* __restrict__ gamma, const float* __restrict__ beta,
        const float* __restrict__ scales, const float* __restrict__ stats,
        const unsigned short* __restrict__ wd_bf, const unsigned short* __restrict__ wu_bf,
        float* __restrict__ out) {
    __shared__ unsigned short hs[64 * 72];    // 9216 B, gelu(h), padded stride 72

    int tile = blockIdx.x, b = blockIdx.y;
    int tid = threadIdx.x;
    int t = task_ids[b];
    float sc = scales[t];
    float s1 = stats[2*b], s2 = stats[2*b+1];
    float mean = s1 * (1.f / NPS);
    float var  = s2 * (1.f / NPS) - mean * mean;
    float rstd = rsqrtf(var + GN_EPS);

    size_t xbase = (size_t)b * NPS + (size_t)tile * 64 * C;

    int wave = tid >> 6, lane = tid & 63;
    int m0 = wave * 16;
    int lr = lane & 15, lg = lane >> 4;

    // ---- GEMM1: h[64 x 64] = x_norm[64 x 768] * Wd^T, A from global ----
    f32x4 acc1[4] = {};
    const unsigned short* wd = wd_bf + t * (R * C);
    const float* xa = x + xbase + (size_t)(m0 + lr) * C;   // this lane's A row
    #pragma unroll 2
    for (int k = 0; k < 24; k++) {
        int col = k * 32 + lg * 8;
        float4 v0 = *reinterpret_cast<const float4*>(xa + col);
        float4 v1 = *reinterpret_cast<const float4*>(xa + col + 4);
        float4 g0 = *reinterpret_cast<const float4*>(gamma + col);
        float4 g1 = *reinterpret_cast<const float4*>(gamma + col + 4);
        float4 t0 = *reinterpret_cast<const float4*>(beta + col);
        float4 t1 = *reinterpret_cast<const float4*>(beta + col + 4);
        // x_norm = x*(rstd*g) + (beta - mean*rstd*g)
        float a0 = rstd * g0.x, a1 = rstd * g0.y, a2_ = rstd * g0.z, a3 = rstd * g0.w;
        float a4 = rstd * g1.x, a5 = rstd * g1.y, a6 = rstd * g1.z, a7 = rstd * g1.w;
        bf16x8 a;
        a[0] = (short)f2bf(v0.x * a0 + (t0.x - mean * a0));
        a[1] = (short)f2bf(v0.y * a1 + (t0.y - mean * a1));
        a[2] = (short)f2bf(v0.z * a2_ + (t0.z - mean * a2_));
        a[3] = (short)f2bf(v0.w * a3 + (t0.w - mean * a3));
        a[4] = (short)f2bf(v1.x * a4 + (t1.x - mean * a4));
        a[5] = (short)f2bf(v1.y * a5 + (t1.y - mean * a5));
        a[6] = (short)f2bf(v1.z * a6 + (t1.z - mean * a6));
        a[7] = (short)f2bf(v1.w * a7 + (t1.w - mean * a7));
        #pragma unroll
        for (int n = 0; n < 4; n++) {
            int r = n * 16 + lr;
            bf16x8 bb = *reinterpret_cast<const bf16x8*>(wd + r * C + k * 32 + lg * 8);
            acc1[n] = __builtin_amdgcn_mfma_f32_16x16x32_bf16(a, bb, acc1[n], 0, 0, 0);
        }
    }

    // ---- exact gelu, h -> LDS (bf16); each wave writes only its own 16 rows ----
    #pragma unroll
    for (int n = 0; n < 4; n++) {
        #pragma unroll
        for (int j = 0; j < 4; j++) {
            float v = acc1[n][j];
            float gel = 0.5f * v * (1.f + erff(v * 0.70710678118f));
            int row = m0 + lg * 4 + j;
            int colh = n * 16 + lr;
            hs[row * 72 + colh] = f2bf(gel);
        }
    }
    __syncthreads();

    // ---- GEMM2: delta[64 x 768] = h[64 x 64] * Wu^T, fused residual ----
    bf16x8 a2[2];
    #pragma unroll
    for (int k2 = 0; k2 < 2; k2++) {
        int row = m0 + lr;
        a2[k2] = *reinterpret_cast<const bf16x8*>(hs + row * 72 + k2 * 32 + lg * 8);
    }
    const unsigned short* wu = wu_bf + t * (C * R);
    float* outp = out + xbase;
    const float* xr = x + xbase;
    for (int cn = 0; cn < 6; cn++) {
        f32x4 acc2[8] = {};
        #pragma unroll
        for (int nf = 0; nf < 8; nf++) {
            int cidx = cn * 128 + nf * 16 + lr;
            #pragma unroll
            for (int k2 = 0; k2 < 2; k2++) {
                bf16x8 bb = *reinterpret_cast<const bf16x8*>(wu + cidx * R + k2 * 32 + lg * 8);
                acc2[nf] = __builtin_amdgcn_mfma_f32_16x16x32_bf16(a2[k2], bb, acc2[nf], 0, 0, 0);
            }
        }
        #pragma unroll
        for (int nf = 0; nf < 8; nf++) {
            #pragma unroll
            for (int j = 0; j < 4; j++) {
                int row = m0 + lg * 4 + j;
                int colo = cn * 128 + nf * 16 + lr;
                int idx = row * C + colo;
                outp[idx] = xr[idx] + sc * acc2[nf][j];
            }
        }
    }
}

extern "C" void kernel_launch(void* const* d_in, const int* in_sizes, int n_in,
                              void* d_out, int out_size, void* d_ws, size_t ws_size,
                              hipStream_t stream) {
    const float* x        = (const float*)d_in[0];
    const int*   task_ids = (const int*)d_in[1];
    const float* gamma    = (const float*)d_in[2];
    const float* beta     = (const float*)d_in[3];
    const float* W_down   = (const float*)d_in[4];
    const float* W_up     = (const float*)d_in[5];
    const float* scales   = (const float*)d_in[6];
    float* out = (float*)d_out;

    // workspace layout: [0,128): stats (16 x {sum,sumsq}); then bf16 weights
    float* stats = (float*)d_ws;
    unsigned short* wd_bf = (unsigned short*)((char*)d_ws + 128);
    unsigned short* wu_bf = wd_bf + T * R * C;

    // 1) zero stats + convert weights (2*98304 float4 jobs / 256 = 768 blocks)
    prep_kernel<<<768, 256, 0, stream>>>(W_down, W_up, stats, wd_bf, wu_bf);
    // 2) per-sample stats
    stats_kernel<<<dim3(48, BATCH), 256, 0, stream>>>(x, stats);
    // 3) fused adapter
    fused_kernel<<<dim3(64, BATCH), 256, 0, stream>>>(
        x, task_ids, gamma, beta, scales, stats, wd_bf, wu_bf, out);
}